// Round 1
// baseline (565.408 us; speedup 1.0000x reference)
//
#include <hip/hip_runtime.h>
#include <cfloat>

#define BL_   32768   // B*L = 8*4096
#define H_    8
#define DH_   128
#define M_    512
#define DIM_  1024

#define TP    64      // positions per block
#define TMC   32      // codebook rows per chunk
#define NCH   (M_ / TMC)   // 16 chunks
#define ZSTR  132     // padded LDS row stride in floats (132%32=4 -> conflict-free-ish)

__global__ __launch_bounds__(256) void vq_kernel(
    const float* __restrict__ z,
    const float* __restrict__ cbk,
    float* __restrict__ out_zq,
    float* __restrict__ out_idx,
    float* __restrict__ out_mind)
{
    __shared__ float zt[TP * ZSTR];      // 33792 B
    __shared__ float cbs[TMC * ZSTR];    // 16896 B
    __shared__ float zsqSh[TP];
    __shared__ float csqSh[TMC];
    __shared__ int   bestIdxSh[TP];

    const int tid = threadIdx.x;
    const int tm  = tid & 15;        // 16 m-threads
    const int tp  = tid >> 4;        // 16 pos-threads
    const int bx  = blockIdx.x;
    const int h       = bx >> 9;            // 512 blocks per head
    const int posBase = (bx & 511) << 6;    // *64

    const float* zBlk = z   + (size_t)posBase * DIM_ + h * DH_;
    const float* cbH  = cbk + (size_t)h * M_ * DH_;

    // ---- stage Z tile: 64 rows x 32 float4
    #pragma unroll
    for (int it = 0; it < 8; ++it) {
        int linear = tid + 256 * it;
        int row = linear >> 5;
        int c4  = linear & 31;
        float4 v = *(const float4*)(zBlk + (size_t)row * DIM_ + (c4 << 2));
        *(float4*)(&zt[row * ZSTR + (c4 << 2)]) = v;
    }
    __syncthreads();

    // per-position |z|^2 (one thread per row)
    if (tid < TP) {
        float4 a = make_float4(0.f, 0.f, 0.f, 0.f);
        #pragma unroll
        for (int c4 = 0; c4 < 32; ++c4) {
            float4 v = *(const float4*)(&zt[tid * ZSTR + (c4 << 2)]);
            a.x = fmaf(v.x, v.x, a.x);
            a.y = fmaf(v.y, v.y, a.y);
            a.z = fmaf(v.z, v.z, a.z);
            a.w = fmaf(v.w, v.w, a.w);
        }
        zsqSh[tid] = (a.x + a.y) + (a.z + a.w);
    }

    float bestD[4];
    int   bestI[4];
    #pragma unroll
    for (int i = 0; i < 4; ++i) { bestD[i] = FLT_MAX; bestI[i] = 0; }

    for (int ch = 0; ch < NCH; ++ch) {
        const int mBase = ch * TMC;

        __syncthreads();   // cbs/csqSh free to overwrite (and zsqSh written before first use)

        // stage CB chunk: 32 rows x 32 float4 -> 4 float4/thread
        #pragma unroll
        for (int it = 0; it < 4; ++it) {
            int linear = tid + 256 * it;
            int row = linear >> 5;
            int c4  = linear & 31;
            float4 v = *(const float4*)(cbH + (size_t)(mBase + row) * DH_ + (c4 << 2));
            *(float4*)(&cbs[row * ZSTR + (c4 << 2)]) = v;
        }
        __syncthreads();

        // per-row |c|^2 for this chunk (one thread per row)
        if (tid < TMC) {
            float4 a = make_float4(0.f, 0.f, 0.f, 0.f);
            #pragma unroll
            for (int c4 = 0; c4 < 32; ++c4) {
                float4 v = *(const float4*)(&cbs[tid * ZSTR + (c4 << 2)]);
                a.x = fmaf(v.x, v.x, a.x);
                a.y = fmaf(v.y, v.y, a.y);
                a.z = fmaf(v.z, v.z, a.z);
                a.w = fmaf(v.w, v.w, a.w);
            }
            csqSh[tid] = (a.x + a.y) + (a.z + a.w);
        }

        // ---- dot products: 4 positions x 2 codes per thread
        float4 acc[4][2];
        #pragma unroll
        for (int i = 0; i < 4; ++i)
            #pragma unroll
            for (int j = 0; j < 2; ++j)
                acc[i][j] = make_float4(0.f, 0.f, 0.f, 0.f);

        #pragma unroll 8
        for (int k4 = 0; k4 < 32; ++k4) {
            float4 za[4], cv[2];
            #pragma unroll
            for (int i = 0; i < 4; ++i)
                za[i] = *(const float4*)(&zt[(tp * 4 + i) * ZSTR + (k4 << 2)]);
            #pragma unroll
            for (int j = 0; j < 2; ++j)
                cv[j] = *(const float4*)(&cbs[(tm + 16 * j) * ZSTR + (k4 << 2)]);
            #pragma unroll
            for (int i = 0; i < 4; ++i) {
                #pragma unroll
                for (int j = 0; j < 2; ++j) {
                    acc[i][j].x = fmaf(za[i].x, cv[j].x, acc[i][j].x);
                    acc[i][j].y = fmaf(za[i].y, cv[j].y, acc[i][j].y);
                    acc[i][j].z = fmaf(za[i].z, cv[j].z, acc[i][j].z);
                    acc[i][j].w = fmaf(za[i].w, cv[j].w, acc[i][j].w);
                }
            }
        }
        __syncthreads();   // csqSh ready; acc complete

        // chunk-end: distances + running argmin (m ascending within thread)
        #pragma unroll
        for (int j = 0; j < 2; ++j) {
            int mloc = tm + 16 * j;
            int m = mBase + mloc;
            float cs = csqSh[mloc];
            #pragma unroll
            for (int i = 0; i < 4; ++i) {
                float cross = (acc[i][j].x + acc[i][j].y) + (acc[i][j].z + acc[i][j].w);
                float d = (zsqSh[tp * 4 + i] + cs) - 2.0f * cross;   // match ref association
                d = fmaxf(d, 0.f);
                if (d < bestD[i]) { bestD[i] = d; bestI[i] = m; }
            }
        }
    }

    // ---- reduce across the 16 m-threads (same wave; xor masks stay in 16-lane group)
    #pragma unroll
    for (int off = 1; off < 16; off <<= 1) {
        #pragma unroll
        for (int i = 0; i < 4; ++i) {
            float od = __shfl_xor(bestD[i], off, 64);
            int   oi = __shfl_xor(bestI[i], off, 64);
            if (od < bestD[i] || (od == bestD[i] && oi < bestI[i])) {
                bestD[i] = od; bestI[i] = oi;
            }
        }
    }

    if (tm == 0) {
        #pragma unroll
        for (int i = 0; i < 4; ++i) {
            int p = tp * 4 + i;
            size_t gpos = (size_t)(posBase + p);
            out_idx [gpos * H_ + h] = (float)bestI[i];
            out_mind[gpos * H_ + h] = bestD[i];
            bestIdxSh[p] = bestI[i];
        }
    }
    __syncthreads();

    // ---- z_q = codebook[h][best_idx] : gather (L2-hot) + coalesced store
    #pragma unroll
    for (int it = 0; it < 8; ++it) {
        int linear = tid + 256 * it;
        int row = linear >> 5;
        int c4  = linear & 31;
        int m = bestIdxSh[row];
        float4 v = *(const float4*)(cbH + (size_t)m * DH_ + (c4 << 2));
        *(float4*)(out_zq + (size_t)(posBase + row) * DIM_ + h * DH_ + (c4 << 2)) = v;
    }
}

extern "C" void kernel_launch(void* const* d_in, const int* in_sizes, int n_in,
                              void* d_out, int out_size, void* d_ws, size_t ws_size,
                              hipStream_t stream) {
    const float* z   = (const float*)d_in[0];
    const float* cbk = (const float*)d_in[1];

    float* zq    = (float*)d_out;
    float* oidx  = zq + (size_t)BL_ * DIM_;          // 33,554,432
    float* omind = oidx + (size_t)BL_ * H_;          // + 262,144

    dim3 grid(( BL_ / TP ) * H_);   // 512 * 8 = 4096 blocks
    dim3 block(256);
    hipLaunchKernelGGL(vq_kernel, grid, block, 0, stream,
                       z, cbk, zq, oidx, omind);
}

// Round 3
// 238.261 us; speedup vs baseline: 2.3731x; 2.3731x over previous
//
#include <hip/hip_runtime.h>
#include <cfloat>
#include <cstdint>

#define H_    8
#define DH_   128
#define M_    512
#define DIM_  1024
#define BL_   32768

#define BPOS    128          // positions per block
#define THREADS 512          // 8 waves
#define NC      256          // codes per chunk
#define NCHUNK  (M_ / NC)    // 2
#define CAP     32
#define EPS     0.02f
#define ZSTR    132          // f32 LDS row stride (132%32=4 -> 2-way banks = free)

typedef _Float16 half8 __attribute__((ext_vector_type(8)));
typedef float floatx4 __attribute__((ext_vector_type(4)));

// dynamic LDS layout (bytes)
#define OFF_ZF   0                        // 128*132*4 = 67584 (z tile, f32)
#define OFF_CB   (OFF_ZF + 67584)         // 256*256   = 65536 (codebook chunk, f16 swizzled)
#define OFF_ZSQ  (OFF_CB + 65536)         // 128*4     = 512
#define OFF_CSQ  (OFF_ZSQ + 512)          // 256*4     = 1024
#define OFF_D1   (OFF_CSQ + 1024)         // 4*128*4   = 2048
#define OFF_THR  (OFF_D1 + 2048)          // 128*4     = 512
#define OFF_CNT  (OFF_THR + 512)          // 128*4     = 512
#define OFF_CI   (OFF_CNT + 512)          // 128*32*4  = 16384
#define OFF_WIN  (OFF_CI + 16384)         // 128*4     = 512
#define LDS_TOTAL (OFF_WIN + 512)         // 154624 <= 163840

extern __shared__ char smem[];

__device__ __forceinline__ int swz(int row, int g) { return (g ^ (row & 15)) << 4; }

__global__ __launch_bounds__(THREADS) void vq_kernel(
    const float* __restrict__ z,
    const float* __restrict__ cbk,
    float* __restrict__ out_zq,
    float* __restrict__ out_idx,
    float* __restrict__ out_mind)
{
    float* zhF  = (float*)(smem + OFF_ZF);
    char*  cbB  = smem + OFF_CB;
    float* zsqS = (float*)(smem + OFF_ZSQ);
    float* csqS = (float*)(smem + OFF_CSQ);
    float* d1S  = (float*)(smem + OFF_D1);
    float* thrS = (float*)(smem + OFF_THR);
    int*   cntS = (int*)(smem + OFF_CNT);
    int*   candI = (int*)(smem + OFF_CI);
    int*   winS  = (int*)(smem + OFF_WIN);

    const int tid   = threadIdx.x;
    const int lane  = tid & 63;
    const int w     = tid >> 6;
    const int waveM = w >> 2;        // 0..1
    const int waveN = w & 3;         // 0..3
    const int bx    = blockIdx.x;
    const int h     = bx & 7;
    const int posBase = (bx >> 3) * BPOS;

    const float* zBlk = z   + (size_t)posBase * DIM_ + h * DH_;
    const float* cbH  = cbk + (size_t)h * M_ * DH_;

    // ---- stage z tile -> f32 LDS (padded stride)
    #pragma unroll
    for (int it = 0; it < 8; ++it) {
        int g = tid + THREADS * it;          // 0..4095 : 128 rows x 32 float4
        int row = g >> 5, c4 = g & 31;
        float4 v = *(const float4*)(zBlk + (size_t)row * DIM_ + c4 * 4);
        *(float4*)(zhF + row * ZSTR + c4 * 4) = v;
    }
    if (tid < 512) d1S[tid] = FLT_MAX;
    if (tid < BPOS) cntS[tid] = 0;
    __syncthreads();

    // ---- exact f32 zsq per row (round-1 accumulation order)
    if (tid < BPOS) {
        const float* zr = zhF + tid * ZSTR;
        float ax=0.f, ay=0.f, az=0.f, aw=0.f;
        #pragma unroll
        for (int c4 = 0; c4 < 32; ++c4) {
            float4 v = *(const float4*)(zr + c4 * 4);
            ax = fmaf(v.x, v.x, ax); ay = fmaf(v.y, v.y, ay);
            az = fmaf(v.z, v.z, az); aw = fmaf(v.w, v.w, aw);
        }
        zsqS[tid] = (ax + ay) + (az + aw);
    }

    // ---- A-fragments: convert f32 LDS -> f16 regs, persist across chunks
    // 16x16x32 f16: lane holds A[row = lane&15][k-granule g = ks*4 + (lane>>4)]
    half8 afr[4][4];
    #pragma unroll
    for (int mt = 0; mt < 4; ++mt) {
        int row = waveM * 64 + mt * 16 + (lane & 15);
        #pragma unroll
        for (int ks = 0; ks < 4; ++ks) {
            int g = ks * 4 + (lane >> 4);
            const float* p = zhF + row * ZSTR + g * 8;
            float4 v0 = *(const float4*)p;
            float4 v1 = *(const float4*)(p + 4);
            half8 hv;
            hv[0]=(_Float16)v0.x; hv[1]=(_Float16)v0.y; hv[2]=(_Float16)v0.z; hv[3]=(_Float16)v0.w;
            hv[4]=(_Float16)v1.x; hv[5]=(_Float16)v1.y; hv[6]=(_Float16)v1.z; hv[7]=(_Float16)v1.w;
            afr[mt][ks] = hv;
        }
    }

    floatx4 acc[4][4];

    for (int ch = 0; ch < NCHUNK; ++ch) {
        const int mBase = ch * NC;
        __syncthreads();

        // ---- stage codebook chunk f32 -> f16 LDS (16B granules, XOR-swizzled)
        #pragma unroll
        for (int it = 0; it < 8; ++it) {
            int g = tid + THREADS * it;      // 0..4095 : 256 rows x 16 granules
            int row = g >> 4, gr = g & 15;
            const float* src = cbH + (size_t)(mBase + row) * DH_ + gr * 8;
            float4 v0 = *(const float4*)src;
            float4 v1 = *(const float4*)(src + 4);
            half8 hv;
            hv[0]=(_Float16)v0.x; hv[1]=(_Float16)v0.y; hv[2]=(_Float16)v0.z; hv[3]=(_Float16)v0.w;
            hv[4]=(_Float16)v1.x; hv[5]=(_Float16)v1.y; hv[6]=(_Float16)v1.z; hv[7]=(_Float16)v1.w;
            *(half8*)(cbB + row * 256 + swz(row, gr)) = hv;
        }
        __syncthreads();

        // ---- approx csq per code from f16 LDS
        {
            int row = tid >> 1, p = tid & 1;
            float s = 0.f;
            #pragma unroll
            for (int k = 0; k < 8; ++k) {
                int g = p + 2 * k;
                half8 hv = *(const half8*)(cbB + row * 256 + swz(row, g));
                #pragma unroll
                for (int e = 0; e < 8; ++e) { float f = (float)hv[e]; s = fmaf(f, f, s); }
            }
            s += __shfl_xor(s, 1, 2);
            if (p == 0) csqS[row] = s;
        }
        __syncthreads();

        // ---- MFMA K-loop: wave tile 64 pos x 64 codes
        #pragma unroll
        for (int mt = 0; mt < 4; ++mt)
            #pragma unroll
            for (int nt = 0; nt < 4; ++nt)
                acc[mt][nt] = (floatx4){0.f, 0.f, 0.f, 0.f};

        #pragma unroll
        for (int ks = 0; ks < 4; ++ks) {
            half8 bfr[4];
            #pragma unroll
            for (int nt = 0; nt < 4; ++nt) {
                int row = waveN * 64 + nt * 16 + (lane & 15);
                int g = ks * 4 + (lane >> 4);
                bfr[nt] = *(const half8*)(cbB + row * 256 + swz(row, g));
            }
            #pragma unroll
            for (int mt = 0; mt < 4; ++mt)
                #pragma unroll
                for (int nt = 0; nt < 4; ++nt)
                    acc[mt][nt] = __builtin_amdgcn_mfma_f32_16x16x32_f16(
                        afr[mt][ks], bfr[nt], acc[mt][nt], 0, 0, 0);
        }

        // ---- approx val = csq - 2*cross (zsq common-mode; only gates candidacy)
        float cs[4];
        #pragma unroll
        for (int nt = 0; nt < 4; ++nt)
            cs[nt] = csqS[waveN * 64 + nt * 16 + (lane & 15)];

        #pragma unroll
        for (int mt = 0; mt < 4; ++mt) {
            #pragma unroll
            for (int r = 0; r < 4; ++r) {
                float v0 = fmaf(-2.f, acc[mt][0][r], cs[0]);
                float v1 = fmaf(-2.f, acc[mt][1][r], cs[1]);
                float v2 = fmaf(-2.f, acc[mt][2][r], cs[2]);
                float v3 = fmaf(-2.f, acc[mt][3][r], cs[3]);
                float mn = fminf(fminf(v0, v1), fminf(v2, v3));
                mn = fminf(mn, __shfl_xor(mn, 1, 16));
                mn = fminf(mn, __shfl_xor(mn, 2, 16));
                mn = fminf(mn, __shfl_xor(mn, 4, 16));
                mn = fminf(mn, __shfl_xor(mn, 8, 16));
                if ((lane & 15) == 0) {
                    int row = waveM * 64 + mt * 16 + (lane >> 4) * 4 + r;
                    d1S[waveN * 128 + row] = fminf(d1S[waveN * 128 + row], mn);
                }
            }
        }
        __syncthreads();
        if (tid < BPOS) {
            float t = fminf(fminf(d1S[tid], d1S[128 + tid]),
                            fminf(d1S[256 + tid], d1S[384 + tid]));
            thrS[tid] = t + EPS;
        }
        __syncthreads();

        // ---- filter: push candidates within EPS of running approx min
        #pragma unroll
        for (int mt = 0; mt < 4; ++mt) {
            #pragma unroll
            for (int r = 0; r < 4; ++r) {
                int row = waveM * 64 + mt * 16 + (lane >> 4) * 4 + r;
                float thr = thrS[row];
                #pragma unroll
                for (int nt = 0; nt < 4; ++nt) {
                    float v = fmaf(-2.f, acc[mt][nt][r], cs[nt]);
                    if (v <= thr) {
                        int slot = atomicAdd(&cntS[row], 1);
                        if (slot < CAP) {
                            candI[row * CAP + slot] = mBase + waveN * 64 + nt * 16 + (lane & 15);
                        }
                    }
                }
            }
        }
    }
    __syncthreads();

    // ---- rescue: exact fp32 re-rank with REFERENCE arithmetic
    //      d = (zsq + csq) - 2*cross  (zsq≈128 quantizes exactly like jnp's f32 path),
    //      tie -> smaller index (= jnp.argmin first-min). Order-independent -> deterministic.
    {
        int row = tid >> 2, j = tid & 3;
        int cnt = cntS[row]; if (cnt > CAP) cnt = CAP;
        float zsq = zsqS[row];
        const float* zr = zhF + row * ZSTR;
        float bv = FLT_MAX; int bi = 0x7fffffff;
        for (int c = j; c < cnt; c += 4) {
            int m = candI[row * CAP + c];
            const float* cr = cbH + (size_t)m * DH_;
            float cx0=0,cx1=0,cx2=0,cx3=0,cq0=0,cq1=0,cq2=0,cq3=0;
            #pragma unroll 8
            for (int k4 = 0; k4 < 32; ++k4) {
                float4 a = *(const float4*)(zr + k4 * 4);
                float4 b = *(const float4*)(cr + k4 * 4);
                cx0 = fmaf(a.x, b.x, cx0); cx1 = fmaf(a.y, b.y, cx1);
                cx2 = fmaf(a.z, b.z, cx2); cx3 = fmaf(a.w, b.w, cx3);
                cq0 = fmaf(b.x, b.x, cq0); cq1 = fmaf(b.y, b.y, cq1);
                cq2 = fmaf(b.z, b.z, cq2); cq3 = fmaf(b.w, b.w, cq3);
            }
            float cross = (cx0 + cx1) + (cx2 + cx3);
            float csqe  = (cq0 + cq1) + (cq2 + cq3);
            float d = (zsq + csqe) - 2.0f * cross;   // ref association & quantization
            d = fmaxf(d, 0.f);
            if (d < bv || (d == bv && m < bi)) { bv = d; bi = m; }
        }
        #pragma unroll
        for (int off = 1; off < 4; off <<= 1) {
            float ov = __shfl_xor(bv, off, 4);
            int   oi = __shfl_xor(bi, off, 4);
            if (ov < bv || (ov == bv && oi < bi)) { bv = ov; bi = oi; }
        }
        if (j == 0) {
            size_t gp = (size_t)(posBase + row) * H_ + h;
            out_idx[gp]  = (float)bi;
            out_mind[gp] = bv;
            winS[row] = bi;
        }
    }
    __syncthreads();

    // ---- z_q gather (codebook L2-hot) + coalesced store
    #pragma unroll
    for (int it = 0; it < 8; ++it) {
        int gidx = tid + THREADS * it;       // 128 rows x 32 float4
        int row = gidx >> 5, c4 = gidx & 31;
        int m = winS[row];
        float4 v = *(const float4*)(cbH + (size_t)m * DH_ + c4 * 4);
        *(float4*)(out_zq + (size_t)(posBase + row) * DIM_ + h * DH_ + c4 * 4) = v;
    }
}

extern "C" void kernel_launch(void* const* d_in, const int* in_sizes, int n_in,
                              void* d_out, int out_size, void* d_ws, size_t ws_size,
                              hipStream_t stream) {
    const float* z   = (const float*)d_in[0];
    const float* cbk = (const float*)d_in[1];

    float* zq    = (float*)d_out;
    float* oidx  = zq + (size_t)BL_ * DIM_;
    float* omind = oidx + (size_t)BL_ * H_;

    hipFuncSetAttribute((const void*)vq_kernel,
                        hipFuncAttributeMaxDynamicSharedMemorySize, LDS_TOTAL);

    dim3 grid((BL_ / BPOS) * H_);   // 256 * 8 = 2048
    dim3 block(THREADS);
    hipLaunchKernelGGL(vq_kernel, grid, block, LDS_TOTAL, stream,
                       z, cbk, zq, oidx, omind);
}

// Round 7
// 166.069 us; speedup vs baseline: 3.4047x; 1.4347x over previous
//
#include <hip/hip_runtime.h>
#include <cfloat>
#include <cstdint>

#define H_    8
#define DH_   128
#define M_    512
#define DIM_  1024
#define BL_   32768

#define BPOS    128          // positions per block
#define THREADS 512          // 8 waves; wave w owns rows [w*16, w*16+16)
#define NC      128          // codes per chunk
#define NCHUNK  (M_ / NC)    // 4
#define CAP     16
#define EPS     0.02f        // >= 2*maxerr of f16 cross term (maxerr <= ~5e-3 worst case)

typedef _Float16 half8 __attribute__((ext_vector_type(8)));
typedef float floatx4 __attribute__((ext_vector_type(4)));

// dynamic LDS layout (bytes) -- total 75776 <= 81920 -> 2 blocks/CU
#define OFF_Z16  0                        // 128*256 = 32768 (z tile, f16 swizzled)
#define OFF_CB   (OFF_Z16 + 32768)        // 128*256 = 32768 (cb chunk, f16 swizzled)
#define OFF_ZSQ  (OFF_CB + 32768)         // 512  exact f32 |z|^2 (ROUND-1 BIT ORDER)
#define OFF_CSQ  (OFF_ZSQ + 512)          // 512  exact f32 |c|^2 (per chunk, filter only)
#define OFF_CNT  (OFF_CSQ + 512)          // 512
#define OFF_CI   (OFF_CNT + 512)          // 128*CAP*4 = 8192 (candidate indices only)
#define OFF_WIN  (OFF_CI + 8192)          // 512
#define LDS_TOTAL (OFF_WIN + 512)         // 75776

extern __shared__ char smem[];

__device__ __forceinline__ int swz(int row, int g) { return (g ^ (row & 15)) << 4; }

// exact fp32 distance with REFERENCE association: d = (zsq + csq) - 2*cross, clamped.
// Bit-order matches rounds 1/3 (which passed): striped-4 fmaf chains, (a+b)+(c+d) merge.
// DO NOT ALTER ACCUMULATION ORDER — ref ties are resolved at this bit level.
__device__ __forceinline__ float exact_d(const float* __restrict__ zr,
                                         const float* __restrict__ cr,
                                         float zsq)
{
    float cx0=0,cx1=0,cx2=0,cx3=0,cq0=0,cq1=0,cq2=0,cq3=0;
    #pragma unroll 8
    for (int k4 = 0; k4 < 32; ++k4) {
        float4 a = *(const float4*)(zr + k4 * 4);
        float4 b = *(const float4*)(cr + k4 * 4);
        cx0 = fmaf(a.x, b.x, cx0); cx1 = fmaf(a.y, b.y, cx1);
        cx2 = fmaf(a.z, b.z, cx2); cx3 = fmaf(a.w, b.w, cx3);
        cq0 = fmaf(b.x, b.x, cq0); cq1 = fmaf(b.y, b.y, cq1);
        cq2 = fmaf(b.z, b.z, cq2); cq3 = fmaf(b.w, b.w, cq3);
    }
    float cross = (cx0 + cx1) + (cx2 + cx3);
    float csqe  = (cq0 + cq1) + (cq2 + cq3);
    float d = (zsq + csqe) - 2.0f * cross;
    return fmaxf(d, 0.f);
}

__global__ __launch_bounds__(THREADS, 4) void vq_kernel(
    const float* __restrict__ z,
    const float* __restrict__ cbk,
    float* __restrict__ out_zq,
    float* __restrict__ out_idx,
    float* __restrict__ out_mind)
{
    char*  z16  = smem + OFF_Z16;
    char*  cbB  = smem + OFF_CB;
    float* zsqS = (float*)(smem + OFF_ZSQ);
    float* csqS = (float*)(smem + OFF_CSQ);
    int*   cntS = (int*)(smem + OFF_CNT);
    int*   candI = (int*)(smem + OFF_CI);
    int*   winS  = (int*)(smem + OFF_WIN);

    const int tid   = threadIdx.x;
    const int lane  = tid & 63;
    const int w     = tid >> 6;      // wave -> rows [w*16, w*16+16)
    const int bx    = blockIdx.x;
    const int h     = bx & 7;
    const int posBase = (bx >> 3) * BPOS;

    const float* zBlk = z   + (size_t)posBase * DIM_ + h * DH_;
    const float* cbH  = cbk + (size_t)h * M_ * DH_;

    // ---- stage z -> f16 LDS (4 threads/row; conversion only)
    {
        int row = tid >> 2, j = tid & 3;
        const float* zr = zBlk + (size_t)row * DIM_;
        #pragma unroll
        for (int k = 0; k < 4; ++k) {
            int g = j + 4 * k;
            float4 v0 = *(const float4*)(zr + g * 8);
            float4 v1 = *(const float4*)(zr + g * 8 + 4);
            half8 hv;
            hv[0]=(_Float16)v0.x; hv[1]=(_Float16)v0.y; hv[2]=(_Float16)v0.z; hv[3]=(_Float16)v0.w;
            hv[4]=(_Float16)v1.x; hv[5]=(_Float16)v1.y; hv[6]=(_Float16)v1.z; hv[7]=(_Float16)v1.w;
            *(half8*)(z16 + row * 256 + swz(row, g)) = hv;
        }
        if (tid < BPOS) cntS[tid] = 0;
    }

    // ---- exact f32 zsq, ROUND-1 BIT ORDER: one thread per row, striped-4 fmaf
    //      over the row's 32 sequential float4s, merged (ax+ay)+(az+aw).
    if (tid < BPOS) {
        const float* zr = zBlk + (size_t)tid * DIM_;
        float ax=0.f, ay=0.f, az=0.f, aw=0.f;
        #pragma unroll
        for (int c4 = 0; c4 < 32; ++c4) {
            float4 v = *(const float4*)(zr + c4 * 4);
            ax = fmaf(v.x, v.x, ax); ay = fmaf(v.y, v.y, ay);
            az = fmaf(v.z, v.z, az); aw = fmaf(v.w, v.w, aw);
        }
        zsqS[tid] = (ax + ay) + (az + aw);
    }
    // (no sync needed here: first chunk's post-stage sync covers z16/zsqS/cntS)

    half8 afr[4];
    float rmin[4] = {FLT_MAX, FLT_MAX, FLT_MAX, FLT_MAX};

    #pragma unroll
    for (int ch = 0; ch < NCHUNK; ++ch) {
        const int mBase = ch * NC;

        // ---- stage cb chunk -> f16 LDS; f32 csq on the fly (filter use only)
        {
            int row = tid >> 2, j = tid & 3;
            const float* cr = cbH + (size_t)(mBase + row) * DH_;
            float s = 0.f;
            #pragma unroll
            for (int k = 0; k < 4; ++k) {
                int g = j + 4 * k;
                float4 v0 = *(const float4*)(cr + g * 8);
                float4 v1 = *(const float4*)(cr + g * 8 + 4);
                half8 hv;
                hv[0]=(_Float16)v0.x; hv[1]=(_Float16)v0.y; hv[2]=(_Float16)v0.z; hv[3]=(_Float16)v0.w;
                hv[4]=(_Float16)v1.x; hv[5]=(_Float16)v1.y; hv[6]=(_Float16)v1.z; hv[7]=(_Float16)v1.w;
                *(half8*)(cbB + row * 256 + swz(row, g)) = hv;
                s = fmaf(v0.x, v0.x, s); s = fmaf(v0.y, v0.y, s);
                s = fmaf(v0.z, v0.z, s); s = fmaf(v0.w, v0.w, s);
                s = fmaf(v1.x, v1.x, s); s = fmaf(v1.y, v1.y, s);
                s = fmaf(v1.z, v1.z, s); s = fmaf(v1.w, v1.w, s);
            }
            s += __shfl_xor(s, 1, 4);
            s += __shfl_xor(s, 2, 4);
            if (j == 0) csqS[row] = s;
        }
        __syncthreads();

        // ---- A-fragments once (z16 stable after first barrier)
        if (ch == 0) {
            int row = (w << 4) + (lane & 15);
            #pragma unroll
            for (int ks = 0; ks < 4; ++ks)
                afr[ks] = *(const half8*)(z16 + row * 256 + swz(row, ks * 4 + (lane >> 4)));
        }

        // ---- MFMA: this wave's 16 rows x all 128 codes of the chunk
        floatx4 acc[8];
        #pragma unroll
        for (int nt = 0; nt < 8; ++nt) acc[nt] = (floatx4){0.f, 0.f, 0.f, 0.f};

        #pragma unroll
        for (int ks = 0; ks < 4; ++ks) {
            int g = ks * 4 + (lane >> 4);
            half8 bn[8];
            #pragma unroll
            for (int nt = 0; nt < 8; ++nt) {
                int crow = nt * 16 + (lane & 15);
                bn[nt] = *(const half8*)(cbB + crow * 256 + swz(crow, g));
            }
            #pragma unroll
            for (int nt = 0; nt < 8; ++nt)
                acc[nt] = __builtin_amdgcn_mfma_f32_16x16x32_f16(afr[ks], bn[nt], acc[nt], 0, 0, 0);
        }

        // ---- epilogue: v = csq - 2*cross_f16; row-true running min; EPS filter
        float cs[8];
        #pragma unroll
        for (int nt = 0; nt < 8; ++nt) cs[nt] = csqS[nt * 16 + (lane & 15)];
        const int colm = mBase + (lane & 15);

        #pragma unroll
        for (int r = 0; r < 4; ++r) {
            float v[8];
            #pragma unroll
            for (int nt = 0; nt < 8; ++nt) v[nt] = fmaf(-2.f, acc[nt][r], cs[nt]);
            float pm = fminf(fminf(fminf(v[0], v[1]), fminf(v[2], v[3])),
                             fminf(fminf(v[4], v[5]), fminf(v[6], v[7])));
            pm = fminf(pm, __shfl_xor(pm, 1, 16));
            pm = fminf(pm, __shfl_xor(pm, 2, 16));
            pm = fminf(pm, __shfl_xor(pm, 4, 16));
            pm = fminf(pm, __shfl_xor(pm, 8, 16));
            rmin[r] = fminf(rmin[r], pm);
            float thr = rmin[r] + EPS;
            int row = (w << 4) + (lane >> 4) * 4 + r;
            #pragma unroll
            for (int nt = 0; nt < 8; ++nt) {
                if (v[nt] <= thr) {
                    int slot = atomicAdd(&cntS[row], 1);
                    if (slot < CAP) candI[row * CAP + slot] = colm + nt * 16;
                }
            }
        }
        if (ch < NCHUNK - 1) __syncthreads();   // cbB/csqS reused next chunk
    }
    __syncthreads();   // last-chunk pushes visible to rescue

    // ---- rescue: UNCONDITIONAL exact fp32 re-rank (round-1/3 bit order).
    //      Candidate SET is deterministic (only slot order races); lexicographic
    //      (d, m) min over the set is order-independent. Overflow -> full scan.
    {
        int row = tid >> 2, j = tid & 3;
        int cnt = cntS[row];
        float zsq = zsqS[row];
        const float* zr = zBlk + (size_t)row * DIM_;

        float bd = FLT_MAX; int bi = 0x7fffffff;
        if (cnt > CAP) {
            // overflow (rare): racy drop set -> ignore list, deterministic full scan
            for (int m = j; m < M_; m += 4) {
                float d = exact_d(zr, cbH + (size_t)m * DH_, zsq);
                if (d < bd || (d == bd && m < bi)) { bd = d; bi = m; }
            }
        } else {
            for (int c = j; c < cnt; c += 4) {
                int m = candI[row * CAP + c];
                float d = exact_d(zr, cbH + (size_t)m * DH_, zsq);
                if (d < bd || (d == bd && m < bi)) { bd = d; bi = m; }
            }
        }
        #pragma unroll
        for (int off = 1; off < 4; off <<= 1) {
            float od = __shfl_xor(bd, off, 4);
            int   oi = __shfl_xor(bi, off, 4);
            if (od < bd || (od == bd && oi < bi)) { bd = od; bi = oi; }
        }
        if (j == 0) {
            if (bi < 0 || bi >= M_) bi = 0;   // unreachable guard: never fault the gather
            size_t gp = (size_t)(posBase + row) * H_ + h;
            out_idx[gp]  = (float)bi;
            out_mind[gp] = bd;
            winS[row] = bi;
        }
    }
    __syncthreads();

    // ---- z_q gather (cb L2-hot) + coalesced store
    #pragma unroll
    for (int it = 0; it < 8; ++it) {
        int gidx = tid + THREADS * it;       // 128 rows x 32 float4
        int row = gidx >> 5, c4 = gidx & 31;
        int m = winS[row];
        float4 v = *(const float4*)(cbH + (size_t)m * DH_ + c4 * 4);
        *(float4*)(out_zq + (size_t)(posBase + row) * DIM_ + h * DH_ + c4 * 4) = v;
    }
}

extern "C" void kernel_launch(void* const* d_in, const int* in_sizes, int n_in,
                              void* d_out, int out_size, void* d_ws, size_t ws_size,
                              hipStream_t stream) {
    const float* z   = (const float*)d_in[0];
    const float* cbk = (const float*)d_in[1];

    float* zq    = (float*)d_out;
    float* oidx  = zq + (size_t)BL_ * DIM_;
    float* omind = oidx + (size_t)BL_ * H_;

    hipFuncSetAttribute((const void*)vq_kernel,
                        hipFuncAttributeMaxDynamicSharedMemorySize, LDS_TOTAL);

    dim3 grid((BL_ / BPOS) * H_);   // 256 * 8 = 2048
    dim3 block(THREADS);
    hipLaunchKernelGGL(vq_kernel, grid, block, LDS_TOTAL, stream,
                       z, cbk, zq, oidx, omind);
}